// Round 2
// baseline (4077.997 us; speedup 1.0000x reference)
//
#include <hip/hip_runtime.h>

// Problem constants (from reference)
constexpr int kNGene = 40000;
constexpr int kNGoid = 10000;
constexpr int kN     = 50000;
constexpr int kE     = 800000;
constexpr int kInDim = 1280;
constexpr int kH1    = 256;
constexpr int kH2    = 128;
constexpr int kOut   = 64;
constexpr int kGDim  = 4096;
constexpr int kD1    = 1024;

typedef short bf16x8 __attribute__((ext_vector_type(8)));
typedef float f32x4  __attribute__((ext_vector_type(4)));

static __device__ __forceinline__ short f2bf(float f) {
  union { float f; unsigned u; } v; v.f = f;
  unsigned r = v.u + 0x7FFF + ((v.u >> 16) & 1);   // RNE; inputs are finite
  return (short)(r >> 16);
}

// ---------------- degree / norm ----------------
__global__ void k_deg_init(float* deg) {
  int i = blockIdx.x * blockDim.x + threadIdx.x;
  if (i < kN) deg[i] = 1.0f;  // self-loop
}
__global__ void k_deg_count(const int* __restrict__ ei, float* __restrict__ deg) {
  int e = blockIdx.x * blockDim.x + threadIdx.x;
  if (e < kE) atomicAdd(&deg[ei[kE + e]], 1.0f);
}
__global__ void k_rsqrt(float* deg) {
  int i = blockIdx.x * blockDim.x + threadIdx.x;
  if (i < kN) deg[i] = rsqrtf(deg[i]);
}

// ---------------- weight transpose fp32[K][N] -> bf16[N][K] ----------------
// K, N multiples of 32. grid (N/32, K/32), block 256.
__global__ __launch_bounds__(256)
void k_wtrans(const float* __restrict__ W, short* __restrict__ Wt, int K, int N) {
  __shared__ float t[32][33];
  int tx = threadIdx.x & 31, ty = threadIdx.x >> 5;  // 32 x 8
  int n0 = blockIdx.x * 32, k0 = blockIdx.y * 32;
#pragma unroll
  for (int p = 0; p < 4; ++p)
    t[ty + 8 * p][tx] = W[(size_t)(k0 + ty + 8 * p) * N + n0 + tx];
  __syncthreads();
#pragma unroll
  for (int p = 0; p < 4; ++p)
    Wt[(size_t)(n0 + ty + 8 * p) * K + k0 + tx] = f2bf(t[tx][ty + 8 * p]);
}

// ---------------- bf16 MFMA GEMM ----------------
// C[M,N] = A[M,K](fp32, stride lda, converted on the fly) @ B[K,N]
// B given pre-transposed bf16: Bt[N][K]. N multiple of 128, K multiple of 32.
// Tile 128x128, BK=32, 4 waves (2x2), each wave 64x64 via 4x4 frags of 16x16x32.
template <int RELU>
__global__ __launch_bounds__(256)
void k_gemm_bf16(const float* __restrict__ A, int lda,
                 const short* __restrict__ Bt,
                 const float* __restrict__ bias,
                 float* __restrict__ C, int ldc,
                 int M, int K)
{
  __shared__ short As[128 * 40];   // [row][k] pad-40 (80B rows, 16B aligned)
  __shared__ short Bs[128 * 40];   // [col][k] pad-40
  const int tid  = threadIdx.x;
  const int lane = tid & 63;
  const int wid  = tid >> 6;
  const int wr = wid >> 1, wc = wid & 1;
  const int row0 = blockIdx.y * 128;
  const int col0 = blockIdx.x * 128;
  const int l15 = lane & 15, l4 = lane >> 4;

  f32x4 acc[4][4] = {};

  const int sr = tid >> 2;    // 0..63
  const int sc = tid & 3;     // 16B-chunk (8 elems) index

  for (int k0 = 0; k0 < K; k0 += 32) {
    // stage A: 128x32 fp32 -> bf16
#pragma unroll
    for (int p = 0; p < 2; ++p) {
      int r = p * 64 + sr;
      int grow = row0 + r;
      float4 v0 = make_float4(0.f,0.f,0.f,0.f), v1 = v0;
      if (grow < M) {
        const float* ap = A + (size_t)grow * lda + k0 + sc * 8;
        v0 = *reinterpret_cast<const float4*>(ap);
        v1 = *reinterpret_cast<const float4*>(ap + 4);
      }
      bf16x8 t;
      t[0]=f2bf(v0.x); t[1]=f2bf(v0.y); t[2]=f2bf(v0.z); t[3]=f2bf(v0.w);
      t[4]=f2bf(v1.x); t[5]=f2bf(v1.y); t[6]=f2bf(v1.z); t[7]=f2bf(v1.w);
      *reinterpret_cast<bf16x8*>(&As[r * 40 + sc * 8]) = t;
    }
    // stage B: 128 cols x 32 k, already bf16 and contiguous in Bt rows
#pragma unroll
    for (int p = 0; p < 2; ++p) {
      int c = p * 64 + sr;
      *reinterpret_cast<bf16x8*>(&Bs[c * 40 + sc * 8]) =
          *reinterpret_cast<const bf16x8*>(Bt + (size_t)(col0 + c) * K + k0 + sc * 8);
    }
    __syncthreads();

    bf16x8 af[4], bf[4];
#pragma unroll
    for (int m = 0; m < 4; ++m)
      af[m] = *reinterpret_cast<bf16x8*>(&As[(wr * 64 + m * 16 + l15) * 40 + l4 * 8]);
#pragma unroll
    for (int n = 0; n < 4; ++n)
      bf[n] = *reinterpret_cast<bf16x8*>(&Bs[(wc * 64 + n * 16 + l15) * 40 + l4 * 8]);
#pragma unroll
    for (int m = 0; m < 4; ++m)
#pragma unroll
      for (int n = 0; n < 4; ++n)
        acc[m][n] = __builtin_amdgcn_mfma_f32_16x16x32_bf16(af[m], bf[n], acc[m][n], 0, 0, 0);
    __syncthreads();
  }

  // epilogue: C/D layout col=lane&15, row=(lane>>4)*4+e
#pragma unroll
  for (int n = 0; n < 4; ++n) {
    int col = col0 + wc * 64 + n * 16 + l15;
    float bv = bias ? bias[col] : 0.f;
#pragma unroll
    for (int m = 0; m < 4; ++m) {
      int rb = row0 + wr * 64 + m * 16 + l4 * 4;
#pragma unroll
      for (int e = 0; e < 4; ++e) {
        int r = rb + e;
        if (r < M) {
          float v = acc[m][n][e] + bv;
          if (RELU) v = fmaxf(v, 0.f);
          C[(size_t)r * ldc + col] = v;
        }
      }
    }
  }
}

// ---------------- fp32 tiled GEMM (small layers) ----------------
__global__ __launch_bounds__(256)
void k_gemm_f32(const float* __restrict__ A, int lda,
                const float* __restrict__ B, int ldb,
                const float* __restrict__ bias,
                float* __restrict__ C, int ldc,
                int M, int Ncol, int K, int do_relu)
{
  __shared__ float As[16][65];
  __shared__ float Bs[16][68];
  const int tid = threadIdx.x;
  const int tx = tid & 15, ty = tid >> 4;
  const int row0 = blockIdx.y * 64;
  const int col0 = blockIdx.x * 64;
  float acc[4][4] = {};
  for (int k0 = 0; k0 < K; k0 += 16) {
    {
      int r = tid >> 2;
      int c = (tid & 3) << 2;
      int grow = row0 + r;
      float4 v = make_float4(0.f, 0.f, 0.f, 0.f);
      if (grow < M)
        v = *reinterpret_cast<const float4*>(A + (size_t)grow * lda + k0 + c);
      As[c + 0][r] = v.x; As[c + 1][r] = v.y; As[c + 2][r] = v.z; As[c + 3][r] = v.w;
    }
    {
      int r = tid >> 4;
      int c = (tid & 15) << 2;
      int gcol = col0 + c;
      float4 v = make_float4(0.f, 0.f, 0.f, 0.f);
      if (gcol < Ncol)
        v = *reinterpret_cast<const float4*>(B + (size_t)(k0 + r) * ldb + gcol);
      *reinterpret_cast<float4*>(&Bs[r][c]) = v;
    }
    __syncthreads();
#pragma unroll
    for (int k = 0; k < 16; ++k) {
      float a[4], b[4];
#pragma unroll
      for (int i = 0; i < 4; ++i) a[i] = As[k][ty + 16 * i];
#pragma unroll
      for (int j = 0; j < 4; ++j) b[j] = Bs[k][tx + 16 * j];
#pragma unroll
      for (int i = 0; i < 4; ++i)
#pragma unroll
        for (int j = 0; j < 4; ++j)
          acc[i][j] = fmaf(a[i], b[j], acc[i][j]);
    }
    __syncthreads();
  }
#pragma unroll
  for (int i = 0; i < 4; ++i) {
    int r = row0 + ty + 16 * i;
    if (r >= M) continue;
#pragma unroll
    for (int j = 0; j < 4; ++j) {
      int ccol = col0 + tx + 16 * j;
      if (ccol >= Ncol) continue;
      float v = acc[i][j];
      if (bias) v += bias[ccol];
      if (do_relu) v = fmaxf(v, 0.f);
      C[(size_t)r * ldc + ccol] = v;
    }
  }
}

// ---------------- GCN aggregation (only dst < kNGene rows are used) ----------
template <int F>
__global__ void k_self_loop(const float* __restrict__ xw, const float* __restrict__ dinv,
                            float* __restrict__ agg) {
  int idx = blockIdx.x * blockDim.x + threadIdx.x;
  if (idx >= kNGene * F) return;
  int i = idx / F;
  float d = dinv[i];
  agg[idx] = xw[idx] * d * d;
}

template <int F>
__global__ void k_scatter(const int* __restrict__ ei, const float* __restrict__ dinv,
                          const float* __restrict__ xw, float* __restrict__ agg) {
  constexpr int Q = F / 4;                 // float4s per edge
  const int items = kE * Q;
  const int stride = gridDim.x * blockDim.x;
  for (int i = blockIdx.x * blockDim.x + threadIdx.x; i < items; i += stride) {
    int e = i / Q;
    int q = i - e * Q;
    int dst = ei[kE + e];
    if (dst >= kNGene) continue;           // overwritten later; skip
    int src = ei[e];
    float norm = dinv[src] * dinv[dst];
    float4 v = *reinterpret_cast<const float4*>(xw + (size_t)src * F + q * 4);
    float* ap = agg + (size_t)dst * F + q * 4;
    atomicAdd(ap + 0, v.x * norm);
    atomicAdd(ap + 1, v.y * norm);
    atomicAdd(ap + 2, v.z * norm);
    atomicAdd(ap + 3, v.w * norm);
  }
}

template <int F>
__global__ void k_finalize(float* __restrict__ h, const float* __restrict__ bias) {
  int idx = blockIdx.x * blockDim.x + threadIdx.x;
  if (idx >= kNGene * F) return;
  h[idx] = fmaxf(h[idx] + bias[idx & (F - 1)], 0.f);
}

__global__ void k_copy(float* __restrict__ dstp, const float* __restrict__ srcp, int n) {
  int i = blockIdx.x * blockDim.x + threadIdx.x;
  if (i < n) dstp[i] = srcp[i];
}

extern "C" void kernel_launch(void* const* d_in, const int* in_sizes, int n_in,
                              void* d_out, int out_size, void* d_ws, size_t ws_size,
                              hipStream_t stream) {
  const float* x   = (const float*)d_in[0];
  const int*   ei  = (const int*)d_in[1];
  const float* Wd1 = (const float*)d_in[3];
  const float* bd1 = (const float*)d_in[4];
  const float* Wd2 = (const float*)d_in[5];
  const float* bd2 = (const float*)d_in[6];
  const float* W1  = (const float*)d_in[7];
  const float* b1  = (const float*)d_in[8];
  const float* W2  = (const float*)d_in[9];
  const float* b2  = (const float*)d_in[10];
  const float* Wp1 = (const float*)d_in[11];
  const float* bp1 = (const float*)d_in[12];
  const float* Wp2 = (const float*)d_in[13];
  const float* bp2 = (const float*)d_in[14];
  const float* Wf  = (const float*)d_in[15];
  const float* bf  = (const float*)d_in[16];
  float* out = (float*)d_out;
  float* ws  = (float*)d_ws;

  // workspace (floats), peak 51,250,000 fl = 205 MB (same as round 1)
  float* goid_t = ws;                  // 12.8M  (10000 x 1280)
  float* h1tmp  = ws + 12800000;       // 10.24M (10000 x 1024) -> reused as xw2
  float* xw1    = ws + 23040000;       // 12.8M  (50000 x 256)  -> reused as h2
  float* h1     = ws + 35840000;       // 12.8M  (50000 x 256)
  float* p1     = ws + 48640000;       // 2.56M  (10000 x 256)
  float* dinv   = ws + 51200000;       // 50,000
  float* xw2 = h1tmp;
  float* h2  = xw1;
  // transposed bf16 weights live inside h1's region (dead before h1 is written)
  short* wbase = (short*)h1;
  short* Wd1t = wbase;                 // 1024 x 4096 = 4,194,304 shorts
  short* Wd2t = wbase + 4194304;       // 1280 x 1024 = 1,310,720
  short* W1t  = wbase + 5505024;       //  256 x 1280 =   327,680
  short* Wp1t = wbase + 5832704;       //  256 x 1280 =   327,680

  const float* gene_x = x;                          // rows 0..39999, cols 0..1279, lda=4096
  const float* goid_x = x + (size_t)kNGene * kGDim; // rows 40000..49999, lda=4096

  auto gb = [](int M, int Ncol) { return dim3((unsigned)(Ncol / 128), (unsigned)((M + 127) / 128)); };
  auto gf = [](int M, int Ncol) { return dim3((unsigned)((Ncol + 63) / 64), (unsigned)((M + 63) / 64)); };

  // 0) transpose+convert weights
  k_wtrans<<<dim3(kD1 / 32, kGDim / 32), 256, 0, stream>>>(Wd1, Wd1t, kGDim, kD1);
  k_wtrans<<<dim3(kInDim / 32, kD1 / 32), 256, 0, stream>>>(Wd2, Wd2t, kD1, kInDim);
  k_wtrans<<<dim3(kH1 / 32, kInDim / 32), 256, 0, stream>>>(W1, W1t, kInDim, kH1);
  k_wtrans<<<dim3(kH1 / 32, kInDim / 32), 256, 0, stream>>>(Wp1, Wp1t, kInDim, kH1);

  // 1) symmetric-norm degrees
  k_deg_init<<<(kN + 255) / 256, 256, 0, stream>>>(dinv);
  k_deg_count<<<(kE + 255) / 256, 256, 0, stream>>>(ei, dinv);
  k_rsqrt<<<(kN + 255) / 256, 256, 0, stream>>>(dinv);

  // 2) GOID MLP (bf16 MFMA): h1tmp = relu(goid_x@Wd1+bd1); goid_t = relu(h1tmp@Wd2+bd2)
  k_gemm_bf16<1><<<gb(kNGoid, kD1), 256, 0, stream>>>(goid_x, kGDim, Wd1t, bd1, h1tmp, kD1, kNGoid, kGDim);
  k_gemm_bf16<1><<<gb(kNGoid, kInDim), 256, 0, stream>>>(h1tmp, kD1, Wd2t, bd2, goid_t, kInDim, kNGoid, kD1);

  // 3) xw1 = x_t @ W1 (gene slice direct from x, then goid_t rows)
  k_gemm_bf16<0><<<gb(kNGene, kH1), 256, 0, stream>>>(gene_x, kGDim, W1t, nullptr, xw1, kH1, kNGene, kInDim);
  k_gemm_bf16<0><<<gb(kNGoid, kH1), 256, 0, stream>>>(goid_t, kInDim, W1t, nullptr,
                                                      xw1 + (size_t)kNGene * kH1, kH1, kNGoid, kInDim);

  // 4) p1 = goid_t @ Wp1 + bp1
  k_gemm_bf16<0><<<gb(kNGoid, kH1), 256, 0, stream>>>(goid_t, kInDim, Wp1t, bp1, p1, kH1, kNGoid, kInDim);

  // 5) conv1 aggregation -> h1 (gene rows), goid rows = p1
  k_self_loop<kH1><<<(kNGene * kH1 + 255) / 256, 256, 0, stream>>>(xw1, dinv, h1);
  k_scatter<kH1><<<2048, 256, 0, stream>>>(ei, dinv, xw1, h1);
  k_finalize<kH1><<<(kNGene * kH1 + 255) / 256, 256, 0, stream>>>(h1, b1);
  k_copy<<<(kNGoid * kH1 + 255) / 256, 256, 0, stream>>>(h1 + (size_t)kNGene * kH1, p1, kNGoid * kH1);

  // 6) xw2 = h1 @ W2  (fp32, K=256)
  k_gemm_f32<<<gf(kN, kH2), 256, 0, stream>>>(h1, kH1, W2, kH2, nullptr, xw2, kH2, kN, kH2, kH1, 0);

  // 7) conv2 aggregation -> h2 (gene rows); goid rows = p1@Wp2+bp2
  k_self_loop<kH2><<<(kNGene * kH2 + 255) / 256, 256, 0, stream>>>(xw2, dinv, h2);
  k_scatter<kH2><<<2048, 256, 0, stream>>>(ei, dinv, xw2, h2);
  k_finalize<kH2><<<(kNGene * kH2 + 255) / 256, 256, 0, stream>>>(h2, b2);
  k_gemm_f32<<<gf(kNGoid, kH2), 256, 0, stream>>>(p1, kH1, Wp2, kH2, bp2,
                                                  h2 + (size_t)kNGene * kH2, kH2, kNGoid, kH2, kH1, 0);

  // 8) out = h2 @ Wf + bf
  k_gemm_f32<<<gf(kN, kOut), 256, 0, stream>>>(h2, kH2, Wf, kOut, bf, out, kOut, kN, kOut, kH2, 0);
}

// Round 3
// 1110.456 us; speedup vs baseline: 3.6724x; 3.6724x over previous
//
#include <hip/hip_runtime.h>

// Problem constants (from reference)
constexpr int kNGene = 40000;
constexpr int kNGoid = 10000;
constexpr int kN     = 50000;
constexpr int kE     = 800000;
constexpr int kInDim = 1280;
constexpr int kH1    = 256;
constexpr int kH2    = 128;
constexpr int kOut   = 64;
constexpr int kGDim  = 4096;
constexpr int kD1    = 1024;

typedef short bf16x8 __attribute__((ext_vector_type(8)));
typedef float f32x4  __attribute__((ext_vector_type(4)));

static __device__ __forceinline__ short f2bf(float f) {
  union { float f; unsigned u; } v; v.f = f;
  unsigned r = v.u + 0x7FFF + ((v.u >> 16) & 1);   // RNE; inputs are finite
  return (short)(r >> 16);
}

// ---------------- degree / norm ----------------
__global__ void k_deg_init(float* deg) {
  int i = blockIdx.x * blockDim.x + threadIdx.x;
  if (i < kN) deg[i] = 1.0f;  // self-loop
}
__global__ void k_deg_count(const int* __restrict__ ei, float* __restrict__ deg) {
  int e = blockIdx.x * blockDim.x + threadIdx.x;
  if (e < kE) atomicAdd(&deg[ei[kE + e]], 1.0f);
}
__global__ void k_rsqrt(float* deg) {
  int i = blockIdx.x * blockDim.x + threadIdx.x;
  if (i < kN) deg[i] = rsqrtf(deg[i]);
}

// ---------------- CSR build (dst < kNGene only) ----------------
__global__ void k_zero_i(int* p, int n) {
  int i = blockIdx.x * blockDim.x + threadIdx.x;
  if (i < n) p[i] = 0;
}
__global__ void k_hist(const int* __restrict__ ei, int* __restrict__ cnt) {
  int e = blockIdx.x * blockDim.x + threadIdx.x;
  if (e >= kE) return;
  int dst = ei[kE + e];
  if (dst < kNGene) atomicAdd(&cnt[dst], 1);
}
// exclusive scan of cnt[0..kNGene) -> indptr[0..kNGene]; single block of 1024
__global__ __launch_bounds__(1024)
void k_scan(const int* __restrict__ cnt, int* __restrict__ indptr) {
  __shared__ int sm[1024];
  __shared__ int carry;
  int t = threadIdx.x;
  if (t == 0) carry = 0;
  __syncthreads();
  for (int base = 0; base < kNGene; base += 1024) {
    int v = (base + t < kNGene) ? cnt[base + t] : 0;
    sm[t] = v;
    __syncthreads();
    for (int off = 1; off < 1024; off <<= 1) {
      int x = (t >= off) ? sm[t - off] : 0;
      __syncthreads();
      sm[t] += x;
      __syncthreads();
    }
    int incl = sm[t];
    int total = sm[1023];
    if (base + t < kNGene) indptr[base + t] = carry + incl - v;
    __syncthreads();
    if (t == 0) carry += total;
    __syncthreads();
  }
  if (t == 0) indptr[kNGene] = carry;
}
__global__ void k_copy_i(int* __restrict__ d, const int* __restrict__ s, int n) {
  int i = blockIdx.x * blockDim.x + threadIdx.x;
  if (i < n) d[i] = s[i];
}
__global__ void k_fill(const int* __restrict__ ei, const float* __restrict__ dinv,
                       int* __restrict__ cursor, int* __restrict__ srcs,
                       float* __restrict__ norms) {
  int e = blockIdx.x * blockDim.x + threadIdx.x;
  if (e >= kE) return;
  int dst = ei[kE + e];
  if (dst >= kNGene) return;  // those rows are overwritten later
  int src = ei[e];
  int pos = atomicAdd(&cursor[dst], 1);
  srcs[pos] = src;
  norms[pos] = dinv[src] * dinv[dst];
}

// ---------------- fused gather aggregation + self-loop + bias + relu --------
// one wave per dst row; lane owns F/64 consecutive features
template <int F>
__global__ __launch_bounds__(256)
void k_gather(const float* __restrict__ xw, const float* __restrict__ dinv,
              const int* __restrict__ indptr, const int* __restrict__ srcs,
              const float* __restrict__ norms, const float* __restrict__ bias,
              float* __restrict__ h) {
  constexpr int VEC = F / 64;
  int row = (blockIdx.x * blockDim.x + threadIdx.x) >> 6;
  int lane = threadIdx.x & 63;
  if (row >= kNGene) return;
  float d = dinv[row];
  float acc[VEC];
  const float* xr = xw + (size_t)row * F + lane * VEC;
#pragma unroll
  for (int v = 0; v < VEC; ++v) acc[v] = xr[v] * (d * d);
  int e0 = indptr[row], e1 = indptr[row + 1];
  for (int e = e0; e < e1; ++e) {
    int src = srcs[e];
    float nrm = norms[e];
    const float* xs = xw + (size_t)src * F + lane * VEC;
    if constexpr (VEC == 4) {
      float4 vv = *reinterpret_cast<const float4*>(xs);
      acc[0] += vv.x * nrm; acc[1] += vv.y * nrm;
      acc[2] += vv.z * nrm; acc[3] += vv.w * nrm;
    } else {
      float2 vv = *reinterpret_cast<const float2*>(xs);
      acc[0] += vv.x * nrm; acc[1] += vv.y * nrm;
    }
  }
  float* hp = h + (size_t)row * F + lane * VEC;
#pragma unroll
  for (int v = 0; v < VEC; ++v) hp[v] = fmaxf(acc[v] + bias[lane * VEC + v], 0.f);
}

// ---------------- weight transpose fp32[K][N] -> bf16[N][K] ----------------
__global__ __launch_bounds__(256)
void k_wtrans(const float* __restrict__ W, short* __restrict__ Wt, int K, int N) {
  __shared__ float t[32][33];
  int tx = threadIdx.x & 31, ty = threadIdx.x >> 5;  // 32 x 8
  int n0 = blockIdx.x * 32, k0 = blockIdx.y * 32;
#pragma unroll
  for (int p = 0; p < 4; ++p)
    t[ty + 8 * p][tx] = W[(size_t)(k0 + ty + 8 * p) * N + n0 + tx];
  __syncthreads();
#pragma unroll
  for (int p = 0; p < 4; ++p)
    Wt[(size_t)(n0 + ty + 8 * p) * K + k0 + tx] = f2bf(t[tx][ty + 8 * p]);
}

// ---------------- bf16 MFMA GEMM ----------------
// C[M,N] = A[M,K](fp32, stride lda, converted on the fly) @ B (bf16 Bt[N][K])
// N multiple of 128, K multiple of 32. Tile 128x128, BK=32, 4 waves.
template <int RELU>
__global__ __launch_bounds__(256)
void k_gemm_bf16(const float* __restrict__ A, int lda,
                 const short* __restrict__ Bt,
                 const float* __restrict__ bias,
                 float* __restrict__ C, int ldc,
                 int M, int K)
{
  __shared__ short As[128 * 40];
  __shared__ short Bs[128 * 40];
  const int tid  = threadIdx.x;
  const int lane = tid & 63;
  const int wid  = tid >> 6;
  const int wr = wid >> 1, wc = wid & 1;
  const int row0 = blockIdx.y * 128;
  const int col0 = blockIdx.x * 128;
  const int l15 = lane & 15, l4 = lane >> 4;

  f32x4 acc[4][4] = {};

  const int sr = tid >> 2;
  const int sc = tid & 3;

  for (int k0 = 0; k0 < K; k0 += 32) {
#pragma unroll
    for (int p = 0; p < 2; ++p) {
      int r = p * 64 + sr;
      int grow = row0 + r;
      float4 v0 = make_float4(0.f,0.f,0.f,0.f), v1 = v0;
      if (grow < M) {
        const float* ap = A + (size_t)grow * lda + k0 + sc * 8;
        v0 = *reinterpret_cast<const float4*>(ap);
        v1 = *reinterpret_cast<const float4*>(ap + 4);
      }
      bf16x8 t;
      t[0]=f2bf(v0.x); t[1]=f2bf(v0.y); t[2]=f2bf(v0.z); t[3]=f2bf(v0.w);
      t[4]=f2bf(v1.x); t[5]=f2bf(v1.y); t[6]=f2bf(v1.z); t[7]=f2bf(v1.w);
      *reinterpret_cast<bf16x8*>(&As[r * 40 + sc * 8]) = t;
    }
#pragma unroll
    for (int p = 0; p < 2; ++p) {
      int c = p * 64 + sr;
      *reinterpret_cast<bf16x8*>(&Bs[c * 40 + sc * 8]) =
          *reinterpret_cast<const bf16x8*>(Bt + (size_t)(col0 + c) * K + k0 + sc * 8);
    }
    __syncthreads();

    bf16x8 af[4], bfr[4];
#pragma unroll
    for (int m = 0; m < 4; ++m)
      af[m] = *reinterpret_cast<bf16x8*>(&As[(wr * 64 + m * 16 + l15) * 40 + l4 * 8]);
#pragma unroll
    for (int n = 0; n < 4; ++n)
      bfr[n] = *reinterpret_cast<bf16x8*>(&Bs[(wc * 64 + n * 16 + l15) * 40 + l4 * 8]);
#pragma unroll
    for (int m = 0; m < 4; ++m)
#pragma unroll
      for (int n = 0; n < 4; ++n)
        acc[m][n] = __builtin_amdgcn_mfma_f32_16x16x32_bf16(af[m], bfr[n], acc[m][n], 0, 0, 0);
    __syncthreads();
  }

#pragma unroll
  for (int n = 0; n < 4; ++n) {
    int col = col0 + wc * 64 + n * 16 + l15;
    float bv = bias ? bias[col] : 0.f;
#pragma unroll
    for (int m = 0; m < 4; ++m) {
      int rb = row0 + wr * 64 + m * 16 + l4 * 4;
#pragma unroll
      for (int e = 0; e < 4; ++e) {
        int r = rb + e;
        if (r < M) {
          float v = acc[m][n][e] + bv;
          if (RELU) v = fmaxf(v, 0.f);
          C[(size_t)r * ldc + col] = v;
        }
      }
    }
  }
}

// ---------------- fp32 tiled GEMM (small layers) ----------------
__global__ __launch_bounds__(256)
void k_gemm_f32(const float* __restrict__ A, int lda,
                const float* __restrict__ B, int ldb,
                const float* __restrict__ bias,
                float* __restrict__ C, int ldc,
                int M, int Ncol, int K, int do_relu)
{
  __shared__ float As[16][65];
  __shared__ float Bs[16][68];
  const int tid = threadIdx.x;
  const int tx = tid & 15, ty = tid >> 4;
  const int row0 = blockIdx.y * 64;
  const int col0 = blockIdx.x * 64;
  float acc[4][4] = {};
  for (int k0 = 0; k0 < K; k0 += 16) {
    {
      int r = tid >> 2;
      int c = (tid & 3) << 2;
      int grow = row0 + r;
      float4 v = make_float4(0.f, 0.f, 0.f, 0.f);
      if (grow < M)
        v = *reinterpret_cast<const float4*>(A + (size_t)grow * lda + k0 + c);
      As[c + 0][r] = v.x; As[c + 1][r] = v.y; As[c + 2][r] = v.z; As[c + 3][r] = v.w;
    }
    {
      int r = tid >> 4;
      int c = (tid & 15) << 2;
      int gcol = col0 + c;
      float4 v = make_float4(0.f, 0.f, 0.f, 0.f);
      if (gcol < Ncol)
        v = *reinterpret_cast<const float4*>(B + (size_t)(k0 + r) * ldb + gcol);
      *reinterpret_cast<float4*>(&Bs[r][c]) = v;
    }
    __syncthreads();
#pragma unroll
    for (int k = 0; k < 16; ++k) {
      float a[4], b[4];
#pragma unroll
      for (int i = 0; i < 4; ++i) a[i] = As[k][ty + 16 * i];
#pragma unroll
      for (int j = 0; j < 4; ++j) b[j] = Bs[k][tx + 16 * j];
#pragma unroll
      for (int i = 0; i < 4; ++i)
#pragma unroll
        for (int j = 0; j < 4; ++j)
          acc[i][j] = fmaf(a[i], b[j], acc[i][j]);
    }
    __syncthreads();
  }
#pragma unroll
  for (int i = 0; i < 4; ++i) {
    int r = row0 + ty + 16 * i;
    if (r >= M) continue;
#pragma unroll
    for (int j = 0; j < 4; ++j) {
      int ccol = col0 + tx + 16 * j;
      if (ccol >= Ncol) continue;
      float v = acc[i][j];
      if (bias) v += bias[ccol];
      if (do_relu) v = fmaxf(v, 0.f);
      C[(size_t)r * ldc + ccol] = v;
    }
  }
}

__global__ void k_copy(float* __restrict__ dstp, const float* __restrict__ srcp, int n) {
  int i = blockIdx.x * blockDim.x + threadIdx.x;
  if (i < n) dstp[i] = srcp[i];
}

extern "C" void kernel_launch(void* const* d_in, const int* in_sizes, int n_in,
                              void* d_out, int out_size, void* d_ws, size_t ws_size,
                              hipStream_t stream) {
  const float* x   = (const float*)d_in[0];
  const int*   ei  = (const int*)d_in[1];
  const float* Wd1 = (const float*)d_in[3];
  const float* bd1 = (const float*)d_in[4];
  const float* Wd2 = (const float*)d_in[5];
  const float* bd2 = (const float*)d_in[6];
  const float* W1  = (const float*)d_in[7];
  const float* b1  = (const float*)d_in[8];
  const float* W2  = (const float*)d_in[9];
  const float* b2  = (const float*)d_in[10];
  const float* Wp1 = (const float*)d_in[11];
  const float* bp1 = (const float*)d_in[12];
  const float* Wp2 = (const float*)d_in[13];
  const float* bp2 = (const float*)d_in[14];
  const float* Wf  = (const float*)d_in[15];
  const float* bf  = (const float*)d_in[16];
  float* out = (float*)d_out;
  float* ws  = (float*)d_ws;

  // workspace (floats), peak 51.25M fl = 205 MB (unchanged from round 1/2)
  float* goid_t = ws;                  // 12.8M  (10000 x 1280)
  float* h1tmp  = ws + 12800000;       // 10.24M (10000 x 1024); later: xw2 + CSR
  float* xw1    = ws + 23040000;       // 12.8M  (50000 x 256)  -> reused as h2
  float* h1     = ws + 35840000;       // 12.8M  (50000 x 256)
  float* p1     = ws + 48640000;       // 2.56M  (10000 x 256)
  float* dinv   = ws + 51200000;       // 50,000
  float* xw2 = h1tmp;                  // 50000 x 128 = 6.4M  (first part of h1tmp)
  float* h2  = xw1;                    // 50000 x 128 = 6.4M
  // CSR lives in the tail of the h1tmp region (free after the GOID MLP,
  // not clobbered by xw2 which only needs 6.4M floats)
  int*   indptr = (int*)(h1tmp + 6600000);   //  40,001
  int*   cursor = (int*)(h1tmp + 6640064);   //  40,000
  int*   srcs   = (int*)(h1tmp + 6680064);   // 800,000
  float* norms  =        h1tmp + 7480064;    // 800,000  (end 8,280,064 < 10.24M)
  // transposed bf16 weights live inside h1's region (dead before h1 is written)
  short* wbase = (short*)h1;
  short* Wd1t = wbase;                 // 1024 x 4096
  short* Wd2t = wbase + 4194304;       // 1280 x 1024
  short* W1t  = wbase + 5505024;       //  256 x 1280
  short* Wp1t = wbase + 5832704;       //  256 x 1280

  const float* gene_x = x;                          // rows 0..39999, lda=4096
  const float* goid_x = x + (size_t)kNGene * kGDim; // rows 40000..49999, lda=4096

  auto gb = [](int M, int Ncol) { return dim3((unsigned)(Ncol / 128), (unsigned)((M + 127) / 128)); };
  auto gf = [](int M, int Ncol) { return dim3((unsigned)((Ncol + 63) / 64), (unsigned)((M + 63) / 64)); };

  // 0) transpose+convert weights
  k_wtrans<<<dim3(kD1 / 32, kGDim / 32), 256, 0, stream>>>(Wd1, Wd1t, kGDim, kD1);
  k_wtrans<<<dim3(kInDim / 32, kD1 / 32), 256, 0, stream>>>(Wd2, Wd2t, kD1, kInDim);
  k_wtrans<<<dim3(kH1 / 32, kInDim / 32), 256, 0, stream>>>(W1, W1t, kInDim, kH1);
  k_wtrans<<<dim3(kH1 / 32, kInDim / 32), 256, 0, stream>>>(Wp1, Wp1t, kInDim, kH1);

  // 1) symmetric-norm degrees
  k_deg_init<<<(kN + 255) / 256, 256, 0, stream>>>(dinv);
  k_deg_count<<<(kE + 255) / 256, 256, 0, stream>>>(ei, dinv);
  k_rsqrt<<<(kN + 255) / 256, 256, 0, stream>>>(dinv);

  // 2) GOID MLP (bf16 MFMA) — uses the FULL h1tmp region, so CSR comes after
  k_gemm_bf16<1><<<gb(kNGoid, kD1), 256, 0, stream>>>(goid_x, kGDim, Wd1t, bd1, h1tmp, kD1, kNGoid, kGDim);
  k_gemm_bf16<1><<<gb(kNGoid, kInDim), 256, 0, stream>>>(h1tmp, kD1, Wd2t, bd2, goid_t, kInDim, kNGoid, kD1);

  // 2.5) CSR build (dst < kNGene only); reused by both convs
  k_zero_i<<<(kNGene + 255) / 256, 256, 0, stream>>>(cursor, kNGene);
  k_hist<<<(kE + 255) / 256, 256, 0, stream>>>(ei, cursor);
  k_scan<<<1, 1024, 0, stream>>>(cursor, indptr);
  k_copy_i<<<(kNGene + 255) / 256, 256, 0, stream>>>(cursor, indptr, kNGene);
  k_fill<<<(kE + 255) / 256, 256, 0, stream>>>(ei, dinv, cursor, srcs, norms);

  // 3) xw1 = x_t @ W1 (gene slice direct from x, then goid_t rows)
  k_gemm_bf16<0><<<gb(kNGene, kH1), 256, 0, stream>>>(gene_x, kGDim, W1t, nullptr, xw1, kH1, kNGene, kInDim);
  k_gemm_bf16<0><<<gb(kNGoid, kH1), 256, 0, stream>>>(goid_t, kInDim, W1t, nullptr,
                                                      xw1 + (size_t)kNGene * kH1, kH1, kNGoid, kInDim);

  // 4) p1 = goid_t @ Wp1 + bp1
  k_gemm_bf16<0><<<gb(kNGoid, kH1), 256, 0, stream>>>(goid_t, kInDim, Wp1t, bp1, p1, kH1, kNGoid, kInDim);

  // 5) conv1: fused gather+selfloop+bias+relu -> h1 gene rows; goid rows = p1
  k_gather<kH1><<<(kNGene * 64 + 255) / 256, 256, 0, stream>>>(xw1, dinv, indptr, srcs, norms, b1, h1);
  k_copy<<<(kNGoid * kH1 + 255) / 256, 256, 0, stream>>>(h1 + (size_t)kNGene * kH1, p1, kNGoid * kH1);

  // 6) xw2 = h1 @ W2  (fp32, K=256)
  k_gemm_f32<<<gf(kN, kH2), 256, 0, stream>>>(h1, kH1, W2, kH2, nullptr, xw2, kH2, kN, kH2, kH1, 0);

  // 7) conv2: gather -> h2 gene rows; goid rows = p1@Wp2+bp2
  k_gather<kH2><<<(kNGene * 64 + 255) / 256, 256, 0, stream>>>(xw2, dinv, indptr, srcs, norms, b2, h2);
  k_gemm_f32<<<gf(kNGoid, kH2), 256, 0, stream>>>(p1, kH1, Wp2, kH2, bp2,
                                                  h2 + (size_t)kNGene * kH2, kH2, kNGoid, kH2, kH1, 0);

  // 8) out = h2 @ Wf + bf
  k_gemm_f32<<<gf(kN, kOut), 256, 0, stream>>>(h2, kH2, Wf, kOut, bf, out, kOut, kN, kOut, kH2, 0);
}

// Round 6
// 966.149 us; speedup vs baseline: 4.2209x; 1.1494x over previous
//
#include <hip/hip_runtime.h>

// Problem constants (from reference)
constexpr int kNGene = 40000;
constexpr int kNGoid = 10000;
constexpr int kN     = 50000;
constexpr int kE     = 800000;
constexpr int kInDim = 1280;
constexpr int kH1    = 256;
constexpr int kH2    = 128;
constexpr int kOut   = 64;
constexpr int kGDim  = 4096;
constexpr int kD1    = 1024;

typedef short bf16x8 __attribute__((ext_vector_type(8)));
typedef float f32x4  __attribute__((ext_vector_type(4)));

static __device__ __forceinline__ short f2bf(float f) {
  union { float f; unsigned u; } v; v.f = f;
  unsigned r = v.u + 0x7FFF + ((v.u >> 16) & 1);   // RNE; inputs are finite
  return (short)(r >> 16);
}

// ---------------- fp32 -> bf16 row-block convert ----------------
__global__ __launch_bounds__(256)
void k_cvt_rows(const float* __restrict__ src, int lda, short* __restrict__ dst,
                int rows, int cols) {
  int chunks_per_row = cols >> 3;
  long long total = (long long)rows * chunks_per_row;
  long long stride = (long long)gridDim.x * blockDim.x;
  for (long long i = blockIdx.x * (long long)blockDim.x + threadIdx.x; i < total; i += stride) {
    int r = (int)(i / chunks_per_row);
    int c = (int)(i - (long long)r * chunks_per_row) << 3;
    const float* sp = src + (size_t)r * lda + c;
    float4 v0 = *reinterpret_cast<const float4*>(sp);
    float4 v1 = *reinterpret_cast<const float4*>(sp + 4);
    bf16x8 t;
    t[0]=f2bf(v0.x); t[1]=f2bf(v0.y); t[2]=f2bf(v0.z); t[3]=f2bf(v0.w);
    t[4]=f2bf(v1.x); t[5]=f2bf(v1.y); t[6]=f2bf(v1.z); t[7]=f2bf(v1.w);
    *reinterpret_cast<bf16x8*>(dst + (size_t)r * cols + c) = t;
  }
}

// ---------------- degree / norm ----------------
__global__ void k_deg_init(float* deg) {
  int i = blockIdx.x * blockDim.x + threadIdx.x;
  if (i < kN) deg[i] = 1.0f;  // self-loop
}
__global__ void k_deg_count(const int* __restrict__ ei, float* __restrict__ deg) {
  int e = blockIdx.x * blockDim.x + threadIdx.x;
  if (e < kE) atomicAdd(&deg[ei[kE + e]], 1.0f);
}
__global__ void k_rsqrt(float* deg) {
  int i = blockIdx.x * blockDim.x + threadIdx.x;
  if (i < kN) deg[i] = rsqrtf(deg[i]);
}

// ---------------- CSR build (dst < kNGene only) ----------------
__global__ void k_zero_i(int* p, int n) {
  int i = blockIdx.x * blockDim.x + threadIdx.x;
  if (i < n) p[i] = 0;
}
__global__ void k_hist(const int* __restrict__ ei, int* __restrict__ cnt) {
  int e = blockIdx.x * blockDim.x + threadIdx.x;
  if (e >= kE) return;
  int dst = ei[kE + e];
  if (dst < kNGene) atomicAdd(&cnt[dst], 1);
}
__global__ __launch_bounds__(1024)
void k_scan(const int* __restrict__ cnt, int* __restrict__ indptr) {
  __shared__ int sm[1024];
  __shared__ int carry;
  int t = threadIdx.x;
  if (t == 0) carry = 0;
  __syncthreads();
  for (int base = 0; base < kNGene; base += 1024) {
    int v = (base + t < kNGene) ? cnt[base + t] : 0;
    sm[t] = v;
    __syncthreads();
    for (int off = 1; off < 1024; off <<= 1) {
      int x = (t >= off) ? sm[t - off] : 0;
      __syncthreads();
      sm[t] += x;
      __syncthreads();
    }
    int incl = sm[t];
    int total = sm[1023];
    if (base + t < kNGene) indptr[base + t] = carry + incl - v;
    __syncthreads();
    if (t == 0) carry += total;
    __syncthreads();
  }
  if (t == 0) indptr[kNGene] = carry;
}
__global__ void k_copy_i(int* __restrict__ d, const int* __restrict__ s, int n) {
  int i = blockIdx.x * blockDim.x + threadIdx.x;
  if (i < n) d[i] = s[i];
}
__global__ void k_fill(const int* __restrict__ ei, const float* __restrict__ dinv,
                       int* __restrict__ cursor, int* __restrict__ srcs,
                       float* __restrict__ norms) {
  int e = blockIdx.x * blockDim.x + threadIdx.x;
  if (e >= kE) return;
  int dst = ei[kE + e];
  if (dst >= kNGene) return;  // those rows are overwritten later
  int src = ei[e];
  int pos = atomicAdd(&cursor[dst], 1);
  srcs[pos] = src;
  norms[pos] = dinv[src] * dinv[dst];
}

// ---------------- fused gather aggregation + self-loop + bias + relu --------
// one wave per dst row; lane owns F/64 consecutive features. OBF: bf16 output.
template <int F, int OBF>
__global__ __launch_bounds__(256)
void k_gather(const float* __restrict__ xw, const float* __restrict__ dinv,
              const int* __restrict__ indptr, const int* __restrict__ srcs,
              const float* __restrict__ norms, const float* __restrict__ bias,
              void* __restrict__ hv) {
  constexpr int VEC = F / 64;
  int row = (blockIdx.x * blockDim.x + threadIdx.x) >> 6;
  int lane = threadIdx.x & 63;
  if (row >= kNGene) return;
  float d = dinv[row];
  float acc[VEC];
  const float* xr = xw + (size_t)row * F + lane * VEC;
#pragma unroll
  for (int v = 0; v < VEC; ++v) acc[v] = xr[v] * (d * d);
  int e0 = indptr[row], e1 = indptr[row + 1];
  for (int e = e0; e < e1; ++e) {
    int src = srcs[e];
    float nrm = norms[e];
    const float* xs = xw + (size_t)src * F + lane * VEC;
    if constexpr (VEC == 4) {
      float4 vv = *reinterpret_cast<const float4*>(xs);
      acc[0] += vv.x * nrm; acc[1] += vv.y * nrm;
      acc[2] += vv.z * nrm; acc[3] += vv.w * nrm;
    } else {
      float2 vv = *reinterpret_cast<const float2*>(xs);
      acc[0] += vv.x * nrm; acc[1] += vv.y * nrm;
    }
  }
#pragma unroll
  for (int v = 0; v < VEC; ++v) acc[v] = fmaxf(acc[v] + bias[lane * VEC + v], 0.f);
  if constexpr (OBF) {
    short* hp = (short*)hv + (size_t)row * F + lane * VEC;
    if constexpr (VEC == 4) {
      short4 s4; s4.x = f2bf(acc[0]); s4.y = f2bf(acc[1]); s4.z = f2bf(acc[2]); s4.w = f2bf(acc[3]);
      *reinterpret_cast<short4*>(hp) = s4;
    } else {
      short2 s2; s2.x = f2bf(acc[0]); s2.y = f2bf(acc[1]);
      *reinterpret_cast<short2*>(hp) = s2;
    }
  } else {
    float* hp = (float*)hv + (size_t)row * F + lane * VEC;
#pragma unroll
    for (int v = 0; v < VEC; ++v) hp[v] = acc[v];
  }
}

// ---------------- weight transpose fp32[K][N] -> bf16[N][K] ----------------
__global__ __launch_bounds__(256)
void k_wtrans(const float* __restrict__ W, short* __restrict__ Wt, int K, int N) {
  __shared__ float t[32][33];
  int tx = threadIdx.x & 31, ty = threadIdx.x >> 5;  // 32 x 8
  int n0 = blockIdx.x * 32, k0 = blockIdx.y * 32;
#pragma unroll
  for (int p = 0; p < 4; ++p)
    t[ty + 8 * p][tx] = W[(size_t)(k0 + ty + 8 * p) * N + n0 + tx];
  __syncthreads();
#pragma unroll
  for (int p = 0; p < 4; ++p)
    Wt[(size_t)(n0 + ty + 8 * p) * K + k0 + tx] = f2bf(t[tx][ty + 8 * p]);
}

// ---------------- bf16 MFMA GEMM, A already bf16 ----------------
// C[M,N] = A[M,K] @ B ; A bf16 row-major stride lda, Bt bf16 [N][K].
// N multiple of 128, K multiple of 32. Tile 128x128, BK=32, 4 waves.
template <int RELU, int OBF>
__global__ __launch_bounds__(256)
void k_gemm_bf16a(const short* __restrict__ A, int lda,
                  const short* __restrict__ Bt,
                  const float* __restrict__ bias,
                  void* __restrict__ Cv, int ldc,
                  int M, int K)
{
  __shared__ short As[128 * 40];
  __shared__ short Bs[128 * 40];
  const int tid  = threadIdx.x;
  const int lane = tid & 63;
  const int wid  = tid >> 6;
  const int wr = wid >> 1, wc = wid & 1;
  const int row0 = blockIdx.y * 128;
  const int col0 = blockIdx.x * 128;
  const int l15 = lane & 15, l4 = lane >> 4;

  f32x4 acc[4][4] = {};
  const int sr = tid >> 2;   // 0..63
  const int sc = tid & 3;    // 16B chunk

  for (int k0 = 0; k0 < K; k0 += 32) {
#pragma unroll
    for (int p = 0; p < 2; ++p) {
      int r = p * 64 + sr;
      int grow = row0 + r;
      bf16x8 t = {};
      if (grow < M)
        t = *reinterpret_cast<const bf16x8*>(A + (size_t)grow * lda + k0 + sc * 8);
      *reinterpret_cast<bf16x8*>(&As[r * 40 + sc * 8]) = t;
    }
#pragma unroll
    for (int p = 0; p < 2; ++p) {
      int c = p * 64 + sr;
      *reinterpret_cast<bf16x8*>(&Bs[c * 40 + sc * 8]) =
          *reinterpret_cast<const bf16x8*>(Bt + (size_t)(col0 + c) * K + k0 + sc * 8);
    }
    __syncthreads();

    bf16x8 af[4], bfr[4];
#pragma unroll
    for (int m = 0; m < 4; ++m)
      af[m] = *reinterpret_cast<bf16x8*>(&As[(wr * 64 + m * 16 + l15) * 40 + l4 * 8]);
#pragma unroll
    for (int n = 0; n < 4; ++n)
      bfr[n] = *reinterpret_cast<bf16x8*>(&Bs[(wc * 64 + n * 16 + l15) * 40 + l4 * 8]);
#pragma unroll
    for (int m = 0; m < 4; ++m)
#pragma unroll
      for (int n = 0; n < 4; ++n)
        acc[m][n] = __builtin_amdgcn_mfma_f32_16x16x32_bf16(af[m], bfr[n], acc[m][n], 0, 0, 0);
    __syncthreads();
  }

#pragma unroll
  for (int n = 0; n < 4; ++n) {
    int col = col0 + wc * 64 + n * 16 + l15;
    float bv = bias ? bias[col] : 0.f;
#pragma unroll
    for (int m = 0; m < 4; ++m) {
      int rb = row0 + wr * 64 + m * 16 + l4 * 4;
#pragma unroll
      for (int e = 0; e < 4; ++e) {
        int r = rb + e;
        if (r < M) {
          float v = acc[m][n][e] + bv;
          if (RELU) v = fmaxf(v, 0.f);
          if constexpr (OBF) ((short*)Cv)[(size_t)r * ldc + col] = f2bf(v);
          else               ((float*)Cv)[(size_t)r * ldc + col] = v;
        }
      }
    }
  }
}

// ---------------- bf16 MFMA GEMM, A fp32 converted on the fly ----------------
template <int RELU>
__global__ __launch_bounds__(256)
void k_gemm_bf16f(const float* __restrict__ A, int lda,
                  const short* __restrict__ Bt,
                  const float* __restrict__ bias,
                  float* __restrict__ C, int ldc,
                  int M, int K)
{
  __shared__ short As[128 * 40];
  __shared__ short Bs[128 * 40];
  const int tid  = threadIdx.x;
  const int lane = tid & 63;
  const int wid  = tid >> 6;
  const int wr = wid >> 1, wc = wid & 1;
  const int row0 = blockIdx.y * 128;
  const int col0 = blockIdx.x * 128;
  const int l15 = lane & 15, l4 = lane >> 4;

  f32x4 acc[4][4] = {};
  const int sr = tid >> 2;
  const int sc = tid & 3;

  for (int k0 = 0; k0 < K; k0 += 32) {
#pragma unroll
    for (int p = 0; p < 2; ++p) {
      int r = p * 64 + sr;
      int grow = row0 + r;
      float4 v0 = make_float4(0.f,0.f,0.f,0.f), v1 = v0;
      if (grow < M) {
        const float* ap = A + (size_t)grow * lda + k0 + sc * 8;
        v0 = *reinterpret_cast<const float4*>(ap);
        v1 = *reinterpret_cast<const float4*>(ap + 4);
      }
      bf16x8 t;
      t[0]=f2bf(v0.x); t[1]=f2bf(v0.y); t[2]=f2bf(v0.z); t[3]=f2bf(v0.w);
      t[4]=f2bf(v1.x); t[5]=f2bf(v1.y); t[6]=f2bf(v1.z); t[7]=f2bf(v1.w);
      *reinterpret_cast<bf16x8*>(&As[r * 40 + sc * 8]) = t;
    }
#pragma unroll
    for (int p = 0; p < 2; ++p) {
      int c = p * 64 + sr;
      *reinterpret_cast<bf16x8*>(&Bs[c * 40 + sc * 8]) =
          *reinterpret_cast<const bf16x8*>(Bt + (size_t)(col0 + c) * K + k0 + sc * 8);
    }
    __syncthreads();

    bf16x8 af[4], bfr[4];
#pragma unroll
    for (int m = 0; m < 4; ++m)
      af[m] = *reinterpret_cast<bf16x8*>(&As[(wr * 64 + m * 16 + l15) * 40 + l4 * 8]);
#pragma unroll
    for (int n = 0; n < 4; ++n)
      bfr[n] = *reinterpret_cast<bf16x8*>(&Bs[(wc * 64 + n * 16 + l15) * 40 + l4 * 8]);
#pragma unroll
    for (int m = 0; m < 4; ++m)
#pragma unroll
      for (int n = 0; n < 4; ++n)
        acc[m][n] = __builtin_amdgcn_mfma_f32_16x16x32_bf16(af[m], bfr[n], acc[m][n], 0, 0, 0);
    __syncthreads();
  }

#pragma unroll
  for (int n = 0; n < 4; ++n) {
    int col = col0 + wc * 64 + n * 16 + l15;
    float bv = bias ? bias[col] : 0.f;
#pragma unroll
    for (int m = 0; m < 4; ++m) {
      int rb = row0 + wr * 64 + m * 16 + l4 * 4;
#pragma unroll
      for (int e = 0; e < 4; ++e) {
        int r = rb + e;
        if (r < M) {
          float v = acc[m][n][e] + bv;
          if (RELU) v = fmaxf(v, 0.f);
          C[(size_t)r * ldc + col] = v;
        }
      }
    }
  }
}

// ---------------- fp32 tiled GEMM (small layers) ----------------
__global__ __launch_bounds__(256)
void k_gemm_f32(const float* __restrict__ A, int lda,
                const float* __restrict__ B, int ldb,
                const float* __restrict__ bias,
                float* __restrict__ C, int ldc,
                int M, int Ncol, int K, int do_relu)
{
  __shared__ float As[16][65];
  __shared__ float Bs[16][68];
  const int tid = threadIdx.x;
  const int tx = tid & 15, ty = tid >> 4;
  const int row0 = blockIdx.y * 64;
  const int col0 = blockIdx.x * 64;
  float acc[4][4] = {};
  for (int k0 = 0; k0 < K; k0 += 16) {
    {
      int r = tid >> 2;
      int c = (tid & 3) << 2;
      int grow = row0 + r;
      float4 v = make_float4(0.f, 0.f, 0.f, 0.f);
      if (grow < M)
        v = *reinterpret_cast<const float4*>(A + (size_t)grow * lda + k0 + c);
      As[c + 0][r] = v.x; As[c + 1][r] = v.y; As[c + 2][r] = v.z; As[c + 3][r] = v.w;
    }
    {
      int r = tid >> 4;
      int c = (tid & 15) << 2;
      int gcol = col0 + c;
      float4 v = make_float4(0.f, 0.f, 0.f, 0.f);
      if (gcol < Ncol)
        v = *reinterpret_cast<const float4*>(B + (size_t)(k0 + r) * ldb + gcol);
      *reinterpret_cast<float4*>(&Bs[r][c]) = v;
    }
    __syncthreads();
#pragma unroll
    for (int k = 0; k < 16; ++k) {
      float a[4], b[4];
#pragma unroll
      for (int i = 0; i < 4; ++i) a[i] = As[k][ty + 16 * i];
#pragma unroll
      for (int j = 0; j < 4; ++j) b[j] = Bs[k][tx + 16 * j];
#pragma unroll
      for (int i = 0; i < 4; ++i)
#pragma unroll
        for (int j = 0; j < 4; ++j)
          acc[i][j] = fmaf(a[i], b[j], acc[i][j]);
    }
    __syncthreads();
  }
#pragma unroll
  for (int i = 0; i < 4; ++i) {
    int r = row0 + ty + 16 * i;
    if (r >= M) continue;
#pragma unroll
    for (int j = 0; j < 4; ++j) {
      int ccol = col0 + tx + 16 * j;
      if (ccol >= Ncol) continue;
      float v = acc[i][j];
      if (bias) v += bias[ccol];
      if (do_relu) v = fmaxf(v, 0.f);
      C[(size_t)r * ldc + ccol] = v;
    }
  }
}

extern "C" void kernel_launch(void* const* d_in, const int* in_sizes, int n_in,
                              void* d_out, int out_size, void* d_ws, size_t ws_size,
                              hipStream_t stream) {
  const float* x   = (const float*)d_in[0];
  const int*   ei  = (const int*)d_in[1];
  const float* Wd1 = (const float*)d_in[3];
  const float* bd1 = (const float*)d_in[4];
  const float* Wd2 = (const float*)d_in[5];
  const float* bd2 = (const float*)d_in[6];
  const float* W1  = (const float*)d_in[7];
  const float* b1  = (const float*)d_in[8];
  const float* W2  = (const float*)d_in[9];
  const float* b2  = (const float*)d_in[10];
  const float* Wp1 = (const float*)d_in[11];
  const float* bp1 = (const float*)d_in[12];
  const float* Wp2 = (const float*)d_in[13];
  const float* bp2 = (const float*)d_in[14];
  const float* Wf  = (const float*)d_in[15];
  const float* bf_ = (const float*)d_in[16];
  float* out = (float*)d_out;
  float* ws  = (float*)d_ws;

  // workspace (float offsets), non-overlapping; total ~71.4M floats = 286 MB
  // NOTE: indptr holds kNGene+1 = 40,001 ints. Rounds 4/5 gave it a 40,000-slot
  // gap, so indptr[40000] aliased cursor[0] and k_copy_i zeroed it (row 39999
  // lost all edges). Keep a 64-int pad after indptr.
  short* goidx_bf = (short*)(ws + 0);          // 10000 x 4096 bf16
  short* goidt_bf = (short*)(ws + 20480000);   // 10000 x 1280 bf16
  short* h1tmp_bf = (short*)(ws + 26880000);   // 10000 x 1024 bf16
  short* Wd1t = (short*)(ws + 32000000);       // 1024 x 4096
  short* Wd2t = (short*)(ws + 34097152);       // 1280 x 1024
  short* W1t  = (short*)(ws + 34752512);       //  256 x 1280
  short* Wp1t = (short*)(ws + 34916352);       //  256 x 1280
  short* W2t  = (short*)(ws + 35080192);       //  128 x 256 (ends 35,096,576)
  float* xw1  = ws + 35100000;                 // 50000 x 256 fp32
  short* h1bf = (short*)(ws + 47900000);       // 50000 x 256 bf16
  float* p1   = ws + 54300000;                 // 10000 x 256 fp32
  float* xw2  = ws + 56860000;                 // 50000 x 128 fp32
  float* h2   = ws + 63260000;                 // 50000 x 128 fp32
  float* dinv = ws + 69660000;                 // 50,000 (ends 69,710,000)
  int*   indptr = (int*)(ws + 69710016);       // 40,001 ints (ends 69,750,017)
  int*   cursor = (int*)(ws + 69750080);       // 40,000 (PADDED past indptr end)
  int*   srcs   = (int*)(ws + 69790080);       // 800,000
  float* norms  = ws + 70590080;               // 800,000 (ends 71,390,080)

  const float* gene_x = x;                          // rows 0..39999, lda=4096
  const float* goid_x = x + (size_t)kNGene * kGDim; // rows 40000..49999

  auto gb = [](int M, int Ncol) { return dim3((unsigned)(Ncol / 128), (unsigned)((M + 127) / 128)); };
  auto gf = [](int M, int Ncol) { return dim3((unsigned)((Ncol + 63) / 64), (unsigned)((M + 63) / 64)); };

  // 0) converts: goid_x -> bf16; weights -> bf16 transposed
  k_cvt_rows<<<2048, 256, 0, stream>>>(goid_x, kGDim, goidx_bf, kNGoid, kGDim);
  k_wtrans<<<dim3(kD1 / 32, kGDim / 32), 256, 0, stream>>>(Wd1, Wd1t, kGDim, kD1);
  k_wtrans<<<dim3(kInDim / 32, kD1 / 32), 256, 0, stream>>>(Wd2, Wd2t, kD1, kInDim);
  k_wtrans<<<dim3(kH1 / 32, kInDim / 32), 256, 0, stream>>>(W1, W1t, kInDim, kH1);
  k_wtrans<<<dim3(kH1 / 32, kInDim / 32), 256, 0, stream>>>(Wp1, Wp1t, kInDim, kH1);
  k_wtrans<<<dim3(kH2 / 32, kH1 / 32), 256, 0, stream>>>(W2, W2t, kH1, kH2);

  // 1) symmetric-norm degrees + CSR
  k_deg_init<<<(kN + 255) / 256, 256, 0, stream>>>(dinv);
  k_deg_count<<<(kE + 255) / 256, 256, 0, stream>>>(ei, dinv);
  k_rsqrt<<<(kN + 255) / 256, 256, 0, stream>>>(dinv);
  k_zero_i<<<(kNGene + 255) / 256, 256, 0, stream>>>(cursor, kNGene);
  k_hist<<<(kE + 255) / 256, 256, 0, stream>>>(ei, cursor);
  k_scan<<<1, 1024, 0, stream>>>(cursor, indptr);
  k_copy_i<<<(kNGene + 255) / 256, 256, 0, stream>>>(cursor, indptr, kNGene);
  k_fill<<<(kE + 255) / 256, 256, 0, stream>>>(ei, dinv, cursor, srcs, norms);

  // 2) GOID MLP (bf16-A MFMA): h1tmp = relu(goidx@Wd1+bd1); goid_t = relu(h1tmp@Wd2+bd2)
  k_gemm_bf16a<1,1><<<gb(kNGoid, kD1), 256, 0, stream>>>(goidx_bf, kGDim, Wd1t, bd1,
                                                         h1tmp_bf, kD1, kNGoid, kGDim);
  k_gemm_bf16a<1,1><<<gb(kNGoid, kInDim), 256, 0, stream>>>(h1tmp_bf, kD1, Wd2t, bd2,
                                                            goidt_bf, kInDim, kNGoid, kD1);

  // 3) xw1 = x_t @ W1: gene slice (fp32 on-the-fly) + goid rows (bf16-A)
  k_gemm_bf16f<0><<<gb(kNGene, kH1), 256, 0, stream>>>(gene_x, kGDim, W1t, nullptr,
                                                       xw1, kH1, kNGene, kInDim);
  k_gemm_bf16a<0,0><<<gb(kNGoid, kH1), 256, 0, stream>>>(goidt_bf, kInDim, W1t, nullptr,
                                                         xw1 + (size_t)kNGene * kH1, kH1,
                                                         kNGoid, kInDim);

  // 4) p1 = goid_t @ Wp1 + bp1 (fp32 out; feeds Wp2 GEMM + bf16 h1 rows)
  k_gemm_bf16a<0,0><<<gb(kNGoid, kH1), 256, 0, stream>>>(goidt_bf, kInDim, Wp1t, bp1,
                                                         p1, kH1, kNGoid, kInDim);

  // 5) conv1: gather -> h1 (bf16) gene rows; goid rows = bf16(p1)
  k_gather<kH1,1><<<(kNGene * 64 + 255) / 256, 256, 0, stream>>>(xw1, dinv, indptr, srcs,
                                                                 norms, b1, h1bf);
  k_cvt_rows<<<1024, 256, 0, stream>>>(p1, kH1, h1bf + (size_t)kNGene * kH1, kNGoid, kH1);

  // 6) xw2 = h1 @ W2 (bf16 MFMA)
  k_gemm_bf16a<0,0><<<gb(kN, kH2), 256, 0, stream>>>(h1bf, kH1, W2t, nullptr,
                                                     xw2, kH2, kN, kH1);

  // 7) conv2: gather -> h2 (fp32) gene rows; goid rows = p1@Wp2+bp2 (fp32)
  k_gather<kH2,0><<<(kNGene * 64 + 255) / 256, 256, 0, stream>>>(xw2, dinv, indptr, srcs,
                                                                 norms, b2, h2);
  k_gemm_f32<<<gf(kNGoid, kH2), 256, 0, stream>>>(p1, kH1, Wp2, kH2, bp2,
                                                  h2 + (size_t)kNGene * kH2, kH2,
                                                  kNGoid, kH2, kH1, 0);

  // 8) out = h2 @ Wf + bf
  k_gemm_f32<<<gf(kN, kOut), 256, 0, stream>>>(h2, kH2, Wf, kOut, bf_, out, kOut,
                                               kN, kOut, kH2, 0);
}